// Round 1
// baseline (5113.131 us; speedup 1.0000x reference)
//
#include <hip/hip_runtime.h>
#include <math.h>

// Problem constants
#define BB   128      // batch
#define TT   25       // time steps
#define RR   100      // attention regions
#define DD   512
#define VV   10000
#define HHH  512
#define NG   2048     // 4*H
#define SKC  16       // split-K slices for the per-step z GEMMs

__device__ __forceinline__ float sigm(float x) { return 1.f / (1.f + expf(-x)); }

// -------------------- init: scatter initial hidden state --------------------
// ihs layout (2, 128, 1024): s, b, j. s0=[h0|c0], s1=[h1|c1].
// concat buffer layout per row b (1536): [h0(512) | ctx(512) | h1(512)]
__global__ __launch_bounds__(256) void k_init(const float* __restrict__ ihs,
                                              float* __restrict__ concat,
                                              float* __restrict__ c0,
                                              float* __restrict__ c1) {
  int idx = blockIdx.x * 256 + threadIdx.x;     // < 262144
  int s = idx >> 17;
  int r = idx & 131071;
  int b = r >> 10;
  int j = r & 1023;
  float v = ihs[idx];
  if (s == 0) {
    if (j < 512) concat[b * 1536 + j] = v;
    else         c0[b * 512 + (j - 512)] = v;
  } else {
    if (j < 512) concat[b * 1536 + 1024 + j] = v;
    else         c1[b * 512 + (j - 512)] = v;
  }
}

// -------------------- cnn pooled: max over first 10 regions --------------------
__global__ __launch_bounds__(256) void k_pool(const float* __restrict__ feat,
                                              float* __restrict__ pool) {
  int idx = blockIdx.x * 256 + threadIdx.x;     // < 65536
  int b = idx >> 9, d = idx & 511;
  float m = -3.4e38f;
  #pragma unroll
  for (int r = 0; r < 10; r++)
    m = fmaxf(m, feat[((size_t)b * RR + r) * 512 + d]);
  pool[idx] = m;
}

// -------------------- build Xin (3200 x 1024): [emb(tok[b,t]) | pooled[b]] ----
// row m = t*128 + b
__global__ __launch_bounds__(256) void k_xin(const int* __restrict__ tok,
                                             const float* __restrict__ emb,
                                             const float* __restrict__ pool,
                                             float* __restrict__ xin) {
  int idx = blockIdx.x * 256 + threadIdx.x;     // < 3,276,800
  int m = idx >> 10, k = idx & 1023;
  int t = m >> 7, b = m & 127;
  float v;
  if (k < 512) v = emb[(size_t)tok[b * TT + t] * 512 + k];
  else         v = pool[b * 512 + (k - 512)];
  xin[idx] = v;
}

// -------------------- generic f32 tiled GEMM --------------------
// C = A(MxK, lda) @ B(KxN, ldb) [+ bias]
// 128x128 tile, BK=16, 256 threads, 8x8 per thread, optional split-K over blockIdx.z.
// mode 0: C[m*ldc+n] = acc + bias[n]
// mode 1: logits remap: row m = t*128+b -> out[b*T*V + t*V + n] = acc + bias[n]
// mode 2: split-K partial (no bias): C[z*M*ldc + m*ldc + n] = acc
__global__ __launch_bounds__(256) void gemm_big(
    const float* __restrict__ A, int lda,
    const float* __restrict__ Bm, int ldb,
    const float* __restrict__ bias,
    float* __restrict__ C, int ldc,
    int M, int N, int K, int ksl, int mode) {
  __shared__ float As[16][132];
  __shared__ float Bs[16][132];
  const int tid = threadIdx.x;
  const int tn = tid & 15, tm = tid >> 4;
  const int m0 = blockIdx.y * 128, n0 = blockIdx.x * 128;
  const int kbeg = blockIdx.z * ksl;
  const int kend = kbeg + ksl;

  float acc[8][8];
  #pragma unroll
  for (int i = 0; i < 8; i++)
    #pragma unroll
    for (int j = 0; j < 8; j++) acc[i][j] = 0.f;

  const int akk = tid & 15, amm = tid >> 4;     // A loader: 16 k x 16 m-rows (x8)
  const int bnn = tid & 127, bkk = tid >> 7;    // B loader: 128 n x 2 k-rows (x8)

  for (int k0 = kbeg; k0 < kend; k0 += 16) {
    #pragma unroll
    for (int i = 0; i < 8; i++)
      As[akk][amm + i * 16] =
          A[(size_t)(m0 + amm + i * 16) * lda + (k0 + akk)];
    #pragma unroll
    for (int i = 0; i < 8; i++) {
      int n = n0 + bnn;
      Bs[bkk + i * 2][bnn] =
          (n < N) ? Bm[(size_t)(k0 + bkk + i * 2) * ldb + n] : 0.f;
    }
    __syncthreads();
    #pragma unroll
    for (int k = 0; k < 16; k++) {
      float a[8], bb[8];
      #pragma unroll
      for (int i = 0; i < 8; i++) a[i] = As[k][tm * 8 + i];
      #pragma unroll
      for (int j = 0; j < 8; j++) bb[j] = Bs[k][tn * 8 + j];
      #pragma unroll
      for (int i = 0; i < 8; i++)
        #pragma unroll
        for (int j = 0; j < 8; j++) acc[i][j] += a[i] * bb[j];
    }
    __syncthreads();
  }

  if (mode == 2) {
    float* Cp = C + (size_t)blockIdx.z * M * ldc;
    #pragma unroll
    for (int i = 0; i < 8; i++) {
      int m = m0 + tm * 8 + i;
      #pragma unroll
      for (int j = 0; j < 8; j++) {
        int n = n0 + tn * 8 + j;
        if (n < N) Cp[(size_t)m * ldc + n] = acc[i][j];
      }
    }
  } else if (mode == 0) {
    #pragma unroll
    for (int i = 0; i < 8; i++) {
      int m = m0 + tm * 8 + i;
      #pragma unroll
      for (int j = 0; j < 8; j++) {
        int n = n0 + tn * 8 + j;
        if (n < N) C[(size_t)m * ldc + n] = acc[i][j] + (bias ? bias[n] : 0.f);
      }
    }
  } else {  // mode 1: logits remap
    #pragma unroll
    for (int i = 0; i < 8; i++) {
      int m = m0 + tm * 8 + i;
      int t = m >> 7, b = m & 127;
      #pragma unroll
      for (int j = 0; j < 8; j++) {
        int n = n0 + tn * 8 + j;
        if (n < N)
          C[(size_t)b * (TT * VV) + (size_t)t * VV + n] = acc[i][j] + bias[n];
      }
    }
  }
}

// -------------------- LSTM activation (merges split-K partials) --------------
// z gates: cols [0:512)=i [512:1024)=f [1024:1536)=o [1536:2048)=g
__global__ __launch_bounds__(256) void lstm_act(
    const float* __restrict__ zp, int S,
    const float* __restrict__ xadd,     // X0[t] (includes b0) or null
    const float* __restrict__ bias,     // b1 or null
    float* __restrict__ cbuf,
    float* __restrict__ ch,             // concat + slot offset (stride 1536)
    float* __restrict__ h1all) {        // H1ALL + t*65536 or null
  int idx = blockIdx.x * 256 + threadIdx.x;   // < 65536
  int m = idx >> 9, j = idx & 511;
  float zi = 0.f, zf = 0.f, zo = 0.f, zg = 0.f;
  const float* p = zp + (size_t)m * NG + j;
  for (int s = 0; s < S; s++) {
    zi += p[0]; zf += p[512]; zo += p[1024]; zg += p[1536];
    p += (size_t)BB * NG;
  }
  if (xadd) {
    const float* q = xadd + (size_t)m * NG + j;
    zi += q[0]; zf += q[512]; zo += q[1024]; zg += q[1536];
  }
  if (bias) {
    zi += bias[j]; zf += bias[512 + j]; zo += bias[1024 + j]; zg += bias[1536 + j];
  }
  float c  = cbuf[idx];
  float cn = sigm(zf) * c + sigm(zi) * tanhf(zg);
  float hn = sigm(zo) * tanhf(cn);
  cbuf[idx] = cn;
  ch[m * 1536 + j] = hn;
  if (h1all) h1all[idx] = hn;
}

// -------------------- attention + softmax + context (one block per b) --------
__global__ __launch_bounds__(256) void k_attn(
    const float* __restrict__ concat,
    const float* __restrict__ c0,
    const float* __restrict__ aW,       // (1024, 100)
    const float* __restrict__ ab,
    const float* __restrict__ feat,     // (128, 100, 512)
    float* __restrict__ concat_ctx) {   // concat base; writes [b*1536+512+d]
  __shared__ float s0s[1024];
  __shared__ float al[128];
  __shared__ float red[128];
  int b = blockIdx.x, tid = threadIdx.x;
  for (int i = tid; i < 1024; i += 256)
    s0s[i] = (i < 512) ? concat[b * 1536 + i] : c0[b * 512 + (i - 512)];
  __syncthreads();
  if (tid < 128) al[tid] = -3.4e38f;
  if (tid < RR) {
    float acc = ab[tid];
    #pragma unroll 4
    for (int k = 0; k < 1024; k++) acc += s0s[k] * aW[k * RR + tid];
    al[tid] = acc;
  }
  __syncthreads();
  if (tid < 128) red[tid] = al[tid];
  __syncthreads();
  for (int off = 64; off >= 1; off >>= 1) {
    if (tid < off) red[tid] = fmaxf(red[tid], red[tid + off]);
    __syncthreads();
  }
  float mx = red[0];
  __syncthreads();
  if (tid < 128) red[tid] = (tid < RR) ? expf(al[tid] - mx) : 0.f;
  __syncthreads();
  if (tid < RR) al[tid] = red[tid];
  __syncthreads();
  for (int off = 64; off >= 1; off >>= 1) {
    if (tid < off) red[tid] += red[tid + off];
    __syncthreads();
  }
  float inv = 1.f / red[0];
  __syncthreads();
  if (tid < RR) al[tid] *= inv;
  __syncthreads();
  for (int d = tid; d < 512; d += 256) {
    float acc = 0.f;
    for (int r = 0; r < RR; r++)
      acc += al[r] * feat[((size_t)b * RR + r) * 512 + d];
    concat_ctx[b * 1536 + 512 + d] = acc;
  }
}

// -------------------- final hidden state --------------------
__global__ __launch_bounds__(256) void k_final(
    const float* __restrict__ concat, const float* __restrict__ c0,
    const float* __restrict__ c1, float* __restrict__ out) {
  int idx = blockIdx.x * 256 + threadIdx.x;   // < 262144
  int s = idx >> 17, r = idx & 131071, b = r >> 10, j = r & 1023;
  float v;
  if (s == 0) v = (j < 512) ? concat[b * 1536 + j]        : c0[b * 512 + j - 512];
  else        v = (j < 512) ? concat[b * 1536 + 1024 + j] : c1[b * 512 + j - 512];
  out[(size_t)BB * TT * VV + idx] = v;
}

extern "C" void kernel_launch(void* const* d_in, const int* in_sizes, int n_in,
                              void* d_out, int out_size, void* d_ws, size_t ws_size,
                              hipStream_t stream) {
  const int*   tok  = (const int*)  d_in[0];
  const float* feat = (const float*)d_in[1];
  const float* ihs  = (const float*)d_in[2];
  const float* emb  = (const float*)d_in[3];
  const float* W0   = (const float*)d_in[4];
  const float* b0   = (const float*)d_in[5];
  const float* W1   = (const float*)d_in[6];
  const float* b1   = (const float*)d_in[7];
  const float* aW   = (const float*)d_in[8];
  const float* ab   = (const float*)d_in[9];
  const float* oW   = (const float*)d_in[10];
  const float* ob   = (const float*)d_in[11];
  float* out = (float*)d_out;
  float* ws  = (float*)d_ws;

  // ws layout (floats). XIN (dead after X0 GEMM) aliases H1ALL.
  float* XIN  = ws;                       // 3,276,800
  float* H1A  = ws;                       // 1,638,400 (alias, written after XIN dead)
  float* X0   = ws + 3276800;             // 6,553,600
  float* POOL = X0 + 6553600;             //    65,536
  float* CC   = POOL + 65536;             //   196,608  concat [h0|ctx|h1] per b
  float* C0   = CC + 196608;              //    65,536
  float* C1   = C0 + 65536;               //    65,536
  float* ZP   = C1 + 65536;               // SKC * 262,144 split-K partials
  // total: 14,417,920 floats = 57.7 MB

  k_init<<<1024, 256, 0, stream>>>(ihs, CC, C0, C1);
  k_pool<<<256, 256, 0, stream>>>(feat, POOL);
  k_xin<<<12800, 256, 0, stream>>>(tok, emb, POOL, XIN);

  // X0 = Xin @ W0[0:1024,:] + b0   (3200 x 2048, K=1024)
  gemm_big<<<dim3(16, 25, 1), 256, 0, stream>>>(
      XIN, 1024, W0, NG, b0, X0, NG, 3200, NG, 1024, 1024, 0);

  for (int t = 0; t < TT; t++) {
    // z0 partials = h0 @ W0[1024:1536,:]   (M=128, N=2048, K=512, split-K)
    gemm_big<<<dim3(16, 1, SKC), 256, 0, stream>>>(
        CC, 1536, W0 + 1024 * NG, NG, nullptr, ZP, NG, BB, NG, 512, 512 / SKC, 2);
    // LSTM0 act: z = partials + X0[t]  -> h0 (concat slot 0), c0
    lstm_act<<<256, 256, 0, stream>>>(
        ZP, SKC, X0 + (size_t)t * BB * NG, nullptr, C0, CC, nullptr);
    // attention + softmax + ctx -> concat slot 1
    k_attn<<<128, 256, 0, stream>>>(CC, C0, aW, ab, feat, CC);
    // z1 partials = [h0|ctx|h1] @ W1   (M=128, N=2048, K=1536, split-K)
    gemm_big<<<dim3(16, 1, SKC), 256, 0, stream>>>(
        CC, 1536, W1, NG, nullptr, ZP, NG, BB, NG, 1536, 1536 / SKC, 2);
    // LSTM1 act: z = partials + b1 -> h1 (concat slot 2), c1, H1ALL[t]
    lstm_act<<<256, 256, 0, stream>>>(
        ZP, SKC, nullptr, b1, C1, CC + 1024, H1A + (size_t)t * BB * HHH);
  }

  // logits = H1ALL @ out_W + out_b, remapped to (B, T, V)
  gemm_big<<<dim3(79, 25, 1), 256, 0, stream>>>(
      H1A, 512, oW, VV, ob, out, VV, 3200, VV, 512, 512, 1);
  k_final<<<1024, 256, 0, stream>>>(CC, C0, C1, out);
}

// Round 2
// 2167.714 us; speedup vs baseline: 2.3588x; 2.3588x over previous
//
#include <hip/hip_runtime.h>
#include <math.h>

// Problem constants
#define BB   128      // batch
#define TT   25       // time steps
#define RR   100      // attention regions
#define DD   512
#define VV   10000
#define NG   2048     // 4*H
#define SK   8        // split-K slices for per-step z GEMMs
#define PAD  8        // LDS pad (bf16 elems) -> row stride 144B, conflict-free b128

typedef short bf8   __attribute__((ext_vector_type(8)));  // 8 bf16 in 4 VGPRs
typedef float f32x4 __attribute__((ext_vector_type(4)));

__device__ __forceinline__ float sigm(float x) { return 1.f / (1.f + expf(-x)); }

__device__ __forceinline__ short f2bf(float f) {        // RNE f32 -> bf16
  unsigned u = __float_as_uint(f);
  u += 0x7fffu + ((u >> 16) & 1u);
  return (short)(u >> 16);
}
__device__ __forceinline__ float bf2f(short h) {
  return __uint_as_float(((unsigned)(unsigned short)h) << 16);
}

// ============ init: scatter initial hidden state ============
// ihs (2,128,1024): s0=[h0|c0], s1=[h1|c1]. CCH bf16 per-b row: [h0|ctx|h1] (1536)
__global__ __launch_bounds__(256) void k_init(const float* __restrict__ ihs,
                                              short* __restrict__ CCH,
                                              float* __restrict__ C0,
                                              float* __restrict__ C1) {
  int idx = blockIdx.x * 256 + threadIdx.x;     // < 262144
  int s = idx >> 17, r = idx & 131071, b = r >> 10, j = r & 1023;
  float v = ihs[idx];
  if (s == 0) {
    if (j < 512) CCH[b * 1536 + j] = f2bf(v);
    else         C0[b * 512 + (j - 512)] = v;
  } else {
    if (j < 512) CCH[b * 1536 + 1024 + j] = f2bf(v);
    else         C1[b * 512 + (j - 512)] = v;
  }
}

// ============ cnn pooled: max over first 10 regions ============
__global__ __launch_bounds__(256) void k_pool(const float* __restrict__ feat,
                                              float* __restrict__ pool) {
  int idx = blockIdx.x * 256 + threadIdx.x;     // < 65536
  int b = idx >> 9, d = idx & 511;
  float m = -3.4e38f;
  #pragma unroll
  for (int r = 0; r < 10; r++)
    m = fmaxf(m, feat[((size_t)b * RR + r) * 512 + d]);
  pool[idx] = m;
}

// ============ Xin (3200 x 1024 bf16): [emb(tok[b,t]) | pooled[b]], row m=t*128+b
__global__ __launch_bounds__(256) void k_xin(const int* __restrict__ tok,
                                             const float* __restrict__ emb,
                                             const float* __restrict__ pool,
                                             short* __restrict__ xin) {
  int idx = blockIdx.x * 256 + threadIdx.x;     // < 3,276,800
  int m = idx >> 10, k = idx & 1023;
  int t = m >> 7, b = m & 127;
  float v;
  if (k < 512) v = emb[(size_t)tok[b * TT + t] * 512 + k];
  else         v = pool[b * 512 + (k - 512)];
  xin[idx] = f2bf(v);
}

// ============ tiled transpose + f32->bf16: in (K x N) -> out (N x K) ============
__global__ __launch_bounds__(256) void k_transpose(const float* __restrict__ in,
                                                   short* __restrict__ out,
                                                   int K, int N) {
  __shared__ float tile[32][33];
  int kt = blockIdx.y * 32, nt = blockIdx.x * 32;
  int tx = threadIdx.x & 31, ty = threadIdx.x >> 5;   // 32 x 8
  #pragma unroll
  for (int i = 0; i < 32; i += 8) {
    int k = kt + ty + i, n = nt + tx;
    tile[ty + i][tx] = (n < N) ? in[(size_t)k * N + n] : 0.f;
  }
  __syncthreads();
  #pragma unroll
  for (int i = 0; i < 32; i += 8) {
    int n = nt + ty + i, k = kt + tx;
    if (n < N) out[(size_t)n * K + k] = f2bf(tile[tx][ty + i]);
  }
}

// ============ big MFMA GEMM: C(MxN f32) = A(MxK bf16) @ BT(NxK bf16)^T + bias
// 128x128 tile, BK=64, 256 thr / 4 waves, each wave 64x64 (4x4 frags 16x16x32).
// mode 0: C[m*ldc+n] = acc+bias   mode 1: logits remap out[b*T*V + t*V + n]
__global__ __launch_bounds__(256) void gemm_mfma(
    const short* __restrict__ A, int lda,
    const short* __restrict__ BT, int ldb,
    const float* __restrict__ bias,
    float* __restrict__ C, int ldc,
    int N, int K, int mode) {
  __shared__ short As[128][64 + PAD];
  __shared__ short Bs[128][64 + PAD];
  const int tid = threadIdx.x;
  const int wv = tid >> 6, ln = tid & 63;
  const int m0 = blockIdx.y * 128, n0 = blockIdx.x * 128;
  const int mw = (wv & 1) * 64, nw = (wv >> 1) * 64;
  const int lrow = ln & 15, quad = ln >> 4, lk8 = quad * 8;

  f32x4 acc[4][4] = {};
  for (int k0 = 0; k0 < K; k0 += 64) {
    #pragma unroll
    for (int v = 0; v < 4; v++) {                 // A: 128x64 = 1024 vecs
      int f = v * 256 + tid, r = f >> 3, kk = (f & 7) * 8;
      *(uint4*)&As[r][kk] = *(const uint4*)&A[(size_t)(m0 + r) * lda + k0 + kk];
    }
    #pragma unroll
    for (int v = 0; v < 4; v++) {                 // B^T: 128 n-rows x 64 k
      int f = v * 256 + tid, r = f >> 3, kk = (f & 7) * 8;
      int n = n0 + r;
      uint4 val{0, 0, 0, 0};
      if (n < N) val = *(const uint4*)&BT[(size_t)n * ldb + k0 + kk];
      *(uint4*)&Bs[r][kk] = val;
    }
    __syncthreads();
    #pragma unroll
    for (int ks = 0; ks < 64; ks += 32) {
      bf8 af[4], bf[4];
      #pragma unroll
      for (int i = 0; i < 4; i++)
        af[i] = *(const bf8*)&As[mw + i * 16 + lrow][ks + lk8];
      #pragma unroll
      for (int j = 0; j < 4; j++)
        bf[j] = *(const bf8*)&Bs[nw + j * 16 + lrow][ks + lk8];
      #pragma unroll
      for (int i = 0; i < 4; i++)
        #pragma unroll
        for (int j = 0; j < 4; j++)
          acc[i][j] = __builtin_amdgcn_mfma_f32_16x16x32_bf16(
              af[i], bf[j], acc[i][j], 0, 0, 0);
    }
    __syncthreads();
  }
  #pragma unroll
  for (int i = 0; i < 4; i++) {
    #pragma unroll
    for (int j = 0; j < 4; j++) {
      #pragma unroll
      for (int r = 0; r < 4; r++) {
        int m = m0 + mw + i * 16 + quad * 4 + r;
        int n = n0 + nw + j * 16 + lrow;
        if (n < N) {
          float v = acc[i][j][r] + (bias ? bias[n] : 0.f);
          if (mode == 0) C[(size_t)m * ldc + n] = v;
          else {
            int t = m >> 7, b = m & 127;
            C[(size_t)b * (TT * VV) + (size_t)t * VV + n] = v;
          }
        }
      }
    }
  }
}

// ============ per-step MFMA GEMM, split-K -> ZP[z][128][2048] (f32 partials)
// A = CCH (128 x lda bf16), K-slice = [z*kslice, (z+1)*kslice). Tile 128x64.
__global__ __launch_bounds__(256) void gemm_rec(
    const short* __restrict__ A, int lda,
    const short* __restrict__ BT, int ldb,
    float* __restrict__ ZP, int kslice) {
  __shared__ short As[128][64 + PAD];
  __shared__ short Bs[64][64 + PAD];
  const int tid = threadIdx.x;
  const int wv = tid >> 6, ln = tid & 63;
  const int n0 = blockIdx.x * 64;
  const int kbeg = blockIdx.z * kslice;
  const int mw = (wv & 1) * 64, nw = (wv >> 1) * 32;
  const int lrow = ln & 15, quad = ln >> 4, lk8 = quad * 8;

  f32x4 acc[4][2] = {};
  for (int k0 = kbeg; k0 < kbeg + kslice; k0 += 64) {
    #pragma unroll
    for (int v = 0; v < 4; v++) {                 // A: 128x64
      int f = v * 256 + tid, r = f >> 3, kk = (f & 7) * 8;
      *(uint4*)&As[r][kk] = *(const uint4*)&A[(size_t)r * lda + k0 + kk];
    }
    #pragma unroll
    for (int v = 0; v < 2; v++) {                 // B^T: 64 n-rows x 64 k
      int f = v * 256 + tid, r = f >> 3, kk = (f & 7) * 8;
      *(uint4*)&Bs[r][kk] = *(const uint4*)&BT[(size_t)(n0 + r) * ldb + k0 + kk];
    }
    __syncthreads();
    #pragma unroll
    for (int ks = 0; ks < 64; ks += 32) {
      bf8 af[4], bf[2];
      #pragma unroll
      for (int i = 0; i < 4; i++)
        af[i] = *(const bf8*)&As[mw + i * 16 + lrow][ks + lk8];
      #pragma unroll
      for (int j = 0; j < 2; j++)
        bf[j] = *(const bf8*)&Bs[nw + j * 16 + lrow][ks + lk8];
      #pragma unroll
      for (int i = 0; i < 4; i++)
        #pragma unroll
        for (int j = 0; j < 2; j++)
          acc[i][j] = __builtin_amdgcn_mfma_f32_16x16x32_bf16(
              af[i], bf[j], acc[i][j], 0, 0, 0);
    }
    __syncthreads();
  }
  float* Cp = ZP + (size_t)blockIdx.z * BB * NG;
  #pragma unroll
  for (int i = 0; i < 4; i++)
    #pragma unroll
    for (int j = 0; j < 2; j++)
      #pragma unroll
      for (int r = 0; r < 4; r++) {
        int m = mw + i * 16 + quad * 4 + r;
        int n = n0 + nw + j * 16 + lrow;
        Cp[(size_t)m * NG + n] = acc[i][j][r];
      }
}

// ============ fused LSTM0 activation + attention + context (1 block / b) =====
// gates j: [i|f|o|g] at j, j+512, j+1024, j+1536. X0t carries x-part incl b0.
__global__ __launch_bounds__(256) void act0_attn(
    const float* __restrict__ ZP, const float* __restrict__ X0t,
    float* __restrict__ C0, short* __restrict__ CCH,
    const float* __restrict__ aW, const float* __restrict__ ab,
    const float* __restrict__ feat) {
  __shared__ float s0s[1024];     // [h(512) | c(512)]
  __shared__ float sc[256];
  __shared__ float al[128];
  int b = blockIdx.x, tid = threadIdx.x;
  #pragma unroll
  for (int h = 0; h < 2; h++) {
    int j = h * 256 + tid;
    float zi = 0.f, zf = 0.f, zo = 0.f, zg = 0.f;
    const float* p = ZP + (size_t)b * NG + j;
    #pragma unroll
    for (int s = 0; s < SK; s++) {
      zi += p[0]; zf += p[512]; zo += p[1024]; zg += p[1536];
      p += (size_t)BB * NG;
    }
    const float* q = X0t + (size_t)b * NG + j;
    zi += q[0]; zf += q[512]; zo += q[1024]; zg += q[1536];
    float c  = C0[b * 512 + j];
    float cn = sigm(zf) * c + sigm(zi) * tanhf(zg);
    float hn = sigm(zo) * tanhf(cn);
    C0[b * 512 + j] = cn;
    CCH[b * 1536 + j] = f2bf(hn);
    s0s[j] = hn; s0s[512 + j] = cn;
  }
  __syncthreads();
  // scores: 200 threads, 2 per region (k halves)
  if (tid < 200) {
    int r = tid >> 1, hf = tid & 1;
    float a2 = 0.f;
    #pragma unroll 4
    for (int k = hf * 512; k < hf * 512 + 512; k++)
      a2 += s0s[k] * aW[k * RR + r];
    sc[tid] = a2;
  }
  __syncthreads();
  if (tid < 128) al[tid] = -3.4e38f;
  if (tid < 100) al[tid] = sc[2 * tid] + sc[2 * tid + 1] + ab[tid];
  __syncthreads();
  if (tid < 128) sc[tid] = al[tid];
  __syncthreads();
  for (int off = 64; off; off >>= 1) {
    if (tid < off) sc[tid] = fmaxf(sc[tid], sc[tid + off]);
    __syncthreads();
  }
  float mx = sc[0];
  __syncthreads();
  if (tid < 128) {
    float e = (tid < 100) ? expf(al[tid] - mx) : 0.f;
    al[tid] = e; sc[tid] = e;
  }
  __syncthreads();
  for (int off = 64; off; off >>= 1) {
    if (tid < off) sc[tid] += sc[tid + off];
    __syncthreads();
  }
  float inv = 1.f / sc[0];
  #pragma unroll
  for (int h = 0; h < 2; h++) {
    int d = h * 256 + tid;
    float a2 = 0.f;
    for (int r = 0; r < RR; r++)
      a2 += al[r] * feat[((size_t)b * RR + r) * 512 + d];
    CCH[b * 1536 + 512 + d] = f2bf(a2 * inv);
  }
}

// ============ LSTM1 activation ============
__global__ __launch_bounds__(256) void act1(
    const float* __restrict__ ZP, const float* __restrict__ b1,
    float* __restrict__ C1, short* __restrict__ CCH, short* __restrict__ H1At) {
  int idx = blockIdx.x * 256 + threadIdx.x;   // < 65536
  int m = idx >> 9, j = idx & 511;
  float zi = 0.f, zf = 0.f, zo = 0.f, zg = 0.f;
  const float* p = ZP + (size_t)m * NG + j;
  #pragma unroll
  for (int s = 0; s < SK; s++) {
    zi += p[0]; zf += p[512]; zo += p[1024]; zg += p[1536];
    p += (size_t)BB * NG;
  }
  zi += b1[j]; zf += b1[512 + j]; zo += b1[1024 + j]; zg += b1[1536 + j];
  float c  = C1[idx];
  float cn = sigm(zf) * c + sigm(zi) * tanhf(zg);
  float hn = sigm(zo) * tanhf(cn);
  C1[idx] = cn;
  short hb = f2bf(hn);
  CCH[m * 1536 + 1024 + j] = hb;
  H1At[idx] = hb;
}

// ============ final hidden state ============
__global__ __launch_bounds__(256) void k_final(
    const short* __restrict__ CCH, const float* __restrict__ C0,
    const float* __restrict__ C1, float* __restrict__ out) {
  int idx = blockIdx.x * 256 + threadIdx.x;   // < 262144
  int s = idx >> 17, r = idx & 131071, b = r >> 10, j = r & 1023;
  float v;
  if (s == 0) v = (j < 512) ? bf2f(CCH[b * 1536 + j])        : C0[b * 512 + j - 512];
  else        v = (j < 512) ? bf2f(CCH[b * 1536 + 1024 + j]) : C1[b * 512 + j - 512];
  out[(size_t)BB * TT * VV + idx] = v;
}

extern "C" void kernel_launch(void* const* d_in, const int* in_sizes, int n_in,
                              void* d_out, int out_size, void* d_ws, size_t ws_size,
                              hipStream_t stream) {
  const int*   tok  = (const int*)  d_in[0];
  const float* feat = (const float*)d_in[1];
  const float* ihs  = (const float*)d_in[2];
  const float* emb  = (const float*)d_in[3];
  const float* W0   = (const float*)d_in[4];
  const float* b0   = (const float*)d_in[5];
  const float* W1   = (const float*)d_in[6];
  const float* b1   = (const float*)d_in[7];
  const float* aW   = (const float*)d_in[8];
  const float* ab   = (const float*)d_in[9];
  const float* oW   = (const float*)d_in[10];
  const float* ob   = (const float*)d_in[11];
  float* out = (float*)d_out;
  char*  w   = (char*)d_ws;

  // ws layout (bytes); XIN (dead after X0 GEMM) aliases H1A. Total ~62.1 MiB.
  short* XIN  = (short*)w;                    // 3200x1024 bf16 (6,553,600 B)
  short* H1A  = (short*)w;                    // 3200x512  bf16 (alias)
  float* X0   = (float*)(w + 6553600);        // 3200x2048 f32 (26,214,400 B)
  float* POOL = (float*)(w + 32768000);       // 128x512   f32
  short* CCH  = (short*)(w + 33030144);       // 128x1536  bf16 [h0|ctx|h1]
  float* C0   = (float*)(w + 33423360);       // 128x512   f32
  float* C1   = (float*)(w + 33685504);       // 128x512   f32
  float* ZP   = (float*)(w + 33947648);       // SK x 128 x 2048 f32 (8,388,608 B)
  short* W0xT = (short*)(w + 42336256);       // 2048x1024 bf16
  short* W0hT = (short*)(w + 46530560);       // 2048x512  bf16
  short* W1T  = (short*)(w + 48627712);       // 2048x1536 bf16
  short* oWT  = (short*)(w + 54919168);       // 10000x512 bf16

  k_init<<<1024, 256, 0, stream>>>(ihs, CCH, C0, C1);
  k_pool<<<256, 256, 0, stream>>>(feat, POOL);
  k_xin<<<12800, 256, 0, stream>>>(tok, emb, POOL, XIN);

  // weight transposes (f32 KxN -> bf16 NxK)
  k_transpose<<<dim3(64, 32), 256, 0, stream>>>(W0, W0xT, 1024, 2048);
  k_transpose<<<dim3(64, 16), 256, 0, stream>>>(W0 + 1024 * NG, W0hT, 512, 2048);
  k_transpose<<<dim3(64, 48), 256, 0, stream>>>(W1, W1T, 1536, 2048);
  k_transpose<<<dim3(313, 16), 256, 0, stream>>>(oW, oWT, 512, 10000);

  // X0 = Xin @ W0[:1024] + b0   (3200 x 2048, K=1024)
  gemm_mfma<<<dim3(16, 25), 256, 0, stream>>>(
      XIN, 1024, W0xT, 1024, b0, X0, NG, NG, 1024, 0);

  for (int t = 0; t < TT; t++) {
    // z0 partials: h0(128x512) @ W0h -> ZP   (kslice 64, 8 slices, 256 blocks)
    gemm_rec<<<dim3(32, 1, SK), 256, 0, stream>>>(CCH, 1536, W0hT, 512, ZP, 64);
    act0_attn<<<128, 256, 0, stream>>>(ZP, X0 + (size_t)t * BB * NG,
                                       C0, CCH, aW, ab, feat);
    // z1 partials: [h0|ctx|h1](128x1536) @ W1 -> ZP  (kslice 192)
    gemm_rec<<<dim3(32, 1, SK), 256, 0, stream>>>(CCH, 1536, W1T, 1536, ZP, 192);
    act1<<<256, 256, 0, stream>>>(ZP, b1, C1, CCH, H1A + (size_t)t * BB * DD);
  }

  // logits = H1A @ out_W + out_b, remapped to (B,T,V)
  gemm_mfma<<<dim3(79, 25), 256, 0, stream>>>(
      H1A, 512, oWT, 512, ob, out, VV, VV, 512, 1);
  k_final<<<1024, 256, 0, stream>>>(CCH, C0, C1, out);
}